// Round 3
// baseline (319.207 us; speedup 1.0000x reference)
//
#include <hip/hip_runtime.h>
#include <hip/hip_bf16.h>

typedef __bf16 bf16x8 __attribute__((ext_vector_type(8)));
typedef __bf16 bf16x4 __attribute__((ext_vector_type(4)));
typedef float floatx4 __attribute__((ext_vector_type(4)));

typedef __attribute__((address_space(1))) const void gas_void;
typedef __attribute__((address_space(3))) void las_void;

__device__ inline void async_load16(const void* g, void* l) {
  __builtin_amdgcn_global_load_lds((gas_void*)g, (las_void*)l, 16, 0, 0);
}

// ---- fp32 -> bf16 elementwise convert (n4 = count of float4 groups) ----
__global__ __launch_bounds__(256) void f32_to_bf16_kernel(const float* __restrict__ in,
                                                          __bf16* __restrict__ out, int n4) {
  int i = blockIdx.x * 256 + threadIdx.x;
  if (i < n4) {
    float4 v = ((const float4*)in)[i];
    bf16x4 o = {(__bf16)v.x, (__bf16)v.y, (__bf16)v.z, (__bf16)v.w};
    ((bf16x4*)out)[i] = o;
  }
}

// ---- V [4096][1024] fp32 -> Vt [1024][4096] bf16 ----
__global__ __launch_bounds__(256) void transpose_convert_kernel(const float* __restrict__ V,
                                                                __bf16* __restrict__ Vt) {
  __shared__ float tile[64][65];
  const int bx = blockIdx.x;  // p tile
  const int by = blockIdx.y;  // e tile
  for (int i = threadIdx.x; i < 64 * 64; i += 256) {
    const int r = i >> 6, c = i & 63;
    tile[r][c] = V[(size_t)(bx * 64 + r) * 1024 + by * 64 + c];
  }
  __syncthreads();
  for (int i = threadIdx.x; i < 64 * 64; i += 256) {
    const int r = i >> 6, c = i & 63;
    Vt[(size_t)(by * 64 + r) * 4096 + bx * 64 + c] = (__bf16)tile[c][r];
  }
}

// C = A (MxK bf16, k-contig) x B (N rows of K bf16, k-contig).
// MODE 0: P[m,n] = exp(min(dot/32, 30)) -> bf16 Cb; fused row-sum atomicAdd into lsum.
// MODE 1: out[m,n] = dot / lsum[m] -> fp32 Cf.
// Waves in 2x2; wave tile = (BM/2) x (BN/2); frags 16x16.
template <int MODE, int BM, int BN, int KS, int NS>
__global__ __launch_bounds__(256) void gemm_kernel(const __bf16* __restrict__ A,
                                                   const __bf16* __restrict__ B,
                                                   __bf16* __restrict__ Cb,
                                                   float* __restrict__ Cf,
                                                   float* __restrict__ lsum) {
  constexpr int BK = 32;
  constexpr int WM = BM / 2, WN = BN / 2;
  constexpr int IM = BM / 32, JN = BN / 32;
  constexpr int ABYTES = BM * 64;                 // A tile bytes (BK*2 = 64 B/row)
  constexpr int ROUNDS = (BM + BN) * 64 / 4096;   // 256 thr x 16 B per round
  __shared__ __bf16 As[BM * BK];
  __shared__ __bf16 Bs[BN * BK];
  const int t = threadIdx.x;
  const int lane = t & 63;
  const int w = t >> 6;
  const int wr = w >> 1, wc = w & 1;
  const int m0 = blockIdx.y * BM;
  const int n0 = blockIdx.x * BN;
  const __bf16* Ab = A + (size_t)m0 * KS;
  const __bf16* Bb = B + (size_t)n0 * KS;

  floatx4 acc[IM][JN] = {};

  // precompute per-round staging sources
  const __bf16* gsrc[ROUNDS];
  char* ldst[ROUNDS];
#pragma unroll
  for (int r = 0; r < ROUNDS; ++r) {
    const int f = t * 16 + r * 4096;
    if (f < ABYTES) {
      gsrc[r] = Ab + (size_t)(f >> 6) * KS + ((f & 63) >> 1);
      ldst[r] = (char*)As + f;
    } else {
      const int fb = f - ABYTES;
      gsrc[r] = Bb + (size_t)(fb >> 6) * KS + ((fb & 63) >> 1);
      ldst[r] = (char*)Bs + fb;
    }
  }

  for (int k0 = 0; k0 < KS; k0 += BK) {
#pragma unroll
    for (int r = 0; r < ROUNDS; ++r) async_load16(gsrc[r] + k0, ldst[r]);
    __builtin_amdgcn_s_waitcnt(0);
    __syncthreads();

    bf16x8 aF[IM], bF[JN];
    const int krd = (lane >> 4) * 16;  // quad * 8 elements
#pragma unroll
    for (int i = 0; i < IM; ++i) {
      const int mr = wr * WM + i * 16 + (lane & 15);
      aF[i] = *(const bf16x8*)((const char*)As + mr * 64 + krd);
    }
#pragma unroll
    for (int j = 0; j < JN; ++j) {
      const int nr = wc * WN + j * 16 + (lane & 15);
      bF[j] = *(const bf16x8*)((const char*)Bs + nr * 64 + krd);
    }
#pragma unroll
    for (int i = 0; i < IM; ++i)
#pragma unroll
      for (int j = 0; j < JN; ++j)
        acc[i][j] = __builtin_amdgcn_mfma_f32_16x16x32_bf16(aF[i], bF[j], acc[i][j], 0, 0, 0);
    __syncthreads();
  }

  // C/D layout: col = lane&15, row = (lane>>4)*4 + reg
  const int cm = wr * WM + ((lane >> 4) << 2);
  const int cn = wc * WN + (lane & 15);
  if (MODE == 0) {
#pragma unroll
    for (int i = 0; i < IM; ++i)
#pragma unroll
      for (int r = 0; r < 4; ++r) {
        const int m = m0 + cm + i * 16 + r;
        float rs = 0.f;
#pragma unroll
        for (int j = 0; j < JN; ++j) {
          const float e = __expf(fminf(acc[i][j][r] * 0.03125f, 30.0f));
          rs += e;
          Cb[(size_t)m * NS + n0 + cn + j * 16] = (__bf16)e;
        }
        // reduce across the 16 lanes (bits 0-3); row index lives in bits 4-5
        rs += __shfl_xor(rs, 1, 64);
        rs += __shfl_xor(rs, 2, 64);
        rs += __shfl_xor(rs, 4, 64);
        rs += __shfl_xor(rs, 8, 64);
        if ((lane & 15) == 0) atomicAdd(&lsum[m], rs);
      }
  } else {
#pragma unroll
    for (int i = 0; i < IM; ++i)
#pragma unroll
      for (int r = 0; r < 4; ++r) {
        const int m = m0 + cm + i * 16 + r;
        const float inv = 1.0f / lsum[m];
#pragma unroll
        for (int j = 0; j < JN; ++j)
          Cf[(size_t)m * NS + n0 + cn + j * 16] = acc[i][j][r] * inv;
      }
  }
}

extern "C" void kernel_launch(void* const* d_in, const int* in_sizes, int n_in,
                              void* d_out, int out_size, void* d_ws, size_t ws_size,
                              hipStream_t stream) {
  const float* x = (const float*)d_in[0];  // [8192][1024] fp32
  const float* K = (const float*)d_in[1];  // [4096][1024] fp32
  const float* V = (const float*)d_in[2];  // [4096][1024] fp32
  float* out = (float*)d_out;              // [8192][1024] fp32

  char* ws = (char*)d_ws;
  __bf16* xb = (__bf16*)ws;                        // 16 MiB
  __bf16* Kb = (__bf16*)(ws + (16u << 20));        // 8 MiB
  __bf16* Vt = (__bf16*)(ws + (24u << 20));        // 8 MiB
  __bf16* P  = (__bf16*)(ws + (32u << 20));        // 64 MiB
  float*  l  = (float*)(ws + (96u << 20));         // 32 KiB

  f32_to_bf16_kernel<<<8192, 256, 0, stream>>>(x, xb, 8192 * 1024 / 4);
  f32_to_bf16_kernel<<<4096, 256, 0, stream>>>(K, Kb, 4096 * 1024 / 4);
  transpose_convert_kernel<<<dim3(64, 16), 256, 0, stream>>>(V, Vt);
  hipMemsetAsync(l, 0, 8192 * sizeof(float), stream);
  // P = exp(xb @ Kb^T / 32), fused row sums  (M=8192 N=4096 K=1024)
  gemm_kernel<0, 128, 128, 1024, 4096><<<dim3(32, 64), 256, 0, stream>>>(xb, Kb, P, nullptr, l);
  // out = (P @ Vt-rows) / l  (M=8192 N=1024 K=4096), 64x128 tiles -> 1024 blocks
  gemm_kernel<1, 64, 128, 4096, 1024><<<dim3(8, 128), 256, 0, stream>>>(P, Vt, nullptr, out, l);
}

// Round 4
// 282.464 us; speedup vs baseline: 1.1301x; 1.1301x over previous
//
#include <hip/hip_runtime.h>
#include <hip/hip_bf16.h>

typedef __bf16 bf16x8 __attribute__((ext_vector_type(8)));
typedef __bf16 bf16x4 __attribute__((ext_vector_type(4)));
typedef float floatx4 __attribute__((ext_vector_type(4)));

typedef __attribute__((address_space(1))) const void gas_void;
typedef __attribute__((address_space(3))) void las_void;

__device__ inline void async_load16(const void* g, void* l) {
  __builtin_amdgcn_global_load_lds((gas_void*)g, (las_void*)l, 16, 0, 0);
}

// ---- fp32 -> bf16 elementwise convert (n4 = count of float4 groups) ----
__global__ __launch_bounds__(256) void f32_to_bf16_kernel(const float* __restrict__ in,
                                                          __bf16* __restrict__ out, int n4) {
  int i = blockIdx.x * 256 + threadIdx.x;
  if (i < n4) {
    float4 v = ((const float4*)in)[i];
    bf16x4 o = {(__bf16)v.x, (__bf16)v.y, (__bf16)v.z, (__bf16)v.w};
    ((bf16x4*)out)[i] = o;
  }
}

// ---- V [4096][1024] fp32 -> Vt [1024][4096] bf16 ----
__global__ __launch_bounds__(256) void transpose_convert_kernel(const float* __restrict__ V,
                                                                __bf16* __restrict__ Vt) {
  __shared__ float tile[64][65];
  const int bx = blockIdx.x;  // p tile
  const int by = blockIdx.y;  // e tile
  for (int i = threadIdx.x; i < 64 * 64; i += 256) {
    const int r = i >> 6, c = i & 63;
    tile[r][c] = V[(size_t)(bx * 64 + r) * 1024 + by * 64 + c];
  }
  __syncthreads();
  for (int i = threadIdx.x; i < 64 * 64; i += 256) {
    const int r = i >> 6, c = i & 63;
    Vt[(size_t)(by * 64 + r) * 4096 + bx * 64 + c] = (__bf16)tile[c][r];
  }
}

// C = A (MxK bf16, k-contig) x B (N rows of K bf16, k-contig). 128x128 tile, BK=32.
// Flat-1D grid; XCD swizzle: blocks sharing an A m-tile land on one XCD
// (id%8 assumed XCD round-robin), so the m-tile is fetched from HBM once.
// MODE 0: P[m,n] = exp(min(dot/32,30)) -> bf16 Cb; fused row-sum atomicAdd into lsum.
// MODE 1: out[m,n] = dot / lsum[m] -> fp32 Cf.
template <int MODE, int KS, int NS>
__global__ __launch_bounds__(256) void gemm_kernel(const __bf16* __restrict__ A,
                                                   const __bf16* __restrict__ B,
                                                   __bf16* __restrict__ Cb,
                                                   float* __restrict__ Cf,
                                                   float* __restrict__ lsum) {
  constexpr int BK = 32;
  __shared__ __bf16 As[128 * BK];  // 8 KiB, rows of 64 B
  __shared__ __bf16 Bs[128 * BK];  // 8 KiB
  const int t = threadIdx.x;
  const int lane = t & 63;
  const int w = t >> 6;
  const int wr = w >> 1, wc = w & 1;

  // XCD-aware swizzle: 64 m-tiles, NS/128 n-tiles.
  const int id = blockIdx.x;
  const int g = id & 7;        // XCD (assumed id%8 round-robin)
  const int s = id >> 3;
  const int mt = g * 8 + (s & 7);
  const int nt = s >> 3;
  const int m0 = mt * 128;
  const int n0 = nt * 128;

  const __bf16* Ab = A + (size_t)m0 * KS;
  const __bf16* Bb = B + (size_t)n0 * KS;

  floatx4 acc[4][4] = {};

  // staging: 2 rounds x 256 thr x 16 B = 8 KiB per operand tile
  const int f0 = t * 16;
  const int row0 = f0 >> 6;
  const int ke0 = (f0 & 63) >> 1;
  const int f1 = 4096 + t * 16;
  const int row1 = f1 >> 6;
  const int ke1 = (f1 & 63) >> 1;

  for (int k0 = 0; k0 < KS; k0 += BK) {
    async_load16(Ab + (size_t)row0 * KS + k0 + ke0, (char*)As + f0);
    async_load16(Ab + (size_t)row1 * KS + k0 + ke1, (char*)As + f1);
    async_load16(Bb + (size_t)row0 * KS + k0 + ke0, (char*)Bs + f0);
    async_load16(Bb + (size_t)row1 * KS + k0 + ke1, (char*)Bs + f1);
    __builtin_amdgcn_s_waitcnt(0);
    __syncthreads();

    bf16x8 aF[4], bF[4];
    const int krd = (lane >> 4) * 16;  // quad * 8 elements
#pragma unroll
    for (int i = 0; i < 4; ++i) {
      const int mr = wr * 64 + i * 16 + (lane & 15);
      aF[i] = *(const bf16x8*)((const char*)As + mr * 64 + krd);
    }
#pragma unroll
    for (int j = 0; j < 4; ++j) {
      const int nr = wc * 64 + j * 16 + (lane & 15);
      bF[j] = *(const bf16x8*)((const char*)Bs + nr * 64 + krd);
    }
#pragma unroll
    for (int i = 0; i < 4; ++i)
#pragma unroll
      for (int j = 0; j < 4; ++j)
        acc[i][j] = __builtin_amdgcn_mfma_f32_16x16x32_bf16(aF[i], bF[j], acc[i][j], 0, 0, 0);
    __syncthreads();
  }

  // C/D layout: col = lane&15, row = (lane>>4)*4 + reg
  const int cm = wr * 64 + ((lane >> 4) << 2);
  const int cn = wc * 64 + (lane & 15);
  if (MODE == 0) {
#pragma unroll
    for (int i = 0; i < 4; ++i)
#pragma unroll
      for (int r = 0; r < 4; ++r) {
        const int m = m0 + cm + i * 16 + r;
        float rs = 0.f;
#pragma unroll
        for (int j = 0; j < 4; ++j) {
          const float e = __expf(fminf(acc[i][j][r] * 0.03125f, 30.0f));
          rs += e;
          Cb[(size_t)m * NS + n0 + cn + j * 16] = (__bf16)e;
        }
        // sum across the 16 lanes of the row-group (lane bits 0-3)
        rs += __shfl_xor(rs, 1, 64);
        rs += __shfl_xor(rs, 2, 64);
        rs += __shfl_xor(rs, 4, 64);
        rs += __shfl_xor(rs, 8, 64);
        if ((lane & 15) == 0) atomicAdd(&lsum[m], rs);
      }
  } else {
#pragma unroll
    for (int i = 0; i < 4; ++i)
#pragma unroll
      for (int r = 0; r < 4; ++r) {
        const int m = m0 + cm + i * 16 + r;
        const float inv = 1.0f / lsum[m];
#pragma unroll
        for (int j = 0; j < 4; ++j)
          Cf[(size_t)m * NS + n0 + cn + j * 16] = acc[i][j][r] * inv;
      }
  }
}

extern "C" void kernel_launch(void* const* d_in, const int* in_sizes, int n_in,
                              void* d_out, int out_size, void* d_ws, size_t ws_size,
                              hipStream_t stream) {
  const float* x = (const float*)d_in[0];  // [8192][1024] fp32
  const float* K = (const float*)d_in[1];  // [4096][1024] fp32
  const float* V = (const float*)d_in[2];  // [4096][1024] fp32
  float* out = (float*)d_out;              // [8192][1024] fp32

  char* ws = (char*)d_ws;
  __bf16* xb = (__bf16*)ws;                        // 16 MiB
  __bf16* Kb = (__bf16*)(ws + (16u << 20));        // 8 MiB
  __bf16* Vt = (__bf16*)(ws + (24u << 20));        // 8 MiB
  __bf16* P  = (__bf16*)(ws + (32u << 20));        // 64 MiB
  float*  l  = (float*)(ws + (96u << 20));         // 32 KiB

  f32_to_bf16_kernel<<<8192, 256, 0, stream>>>(x, xb, 8192 * 1024 / 4);
  f32_to_bf16_kernel<<<4096, 256, 0, stream>>>(K, Kb, 4096 * 1024 / 4);
  transpose_convert_kernel<<<dim3(64, 16), 256, 0, stream>>>(V, Vt);
  hipMemsetAsync(l, 0, 8192 * sizeof(float), stream);
  // P = exp(xb @ Kb^T / 32), fused row sums  (M=8192 N=4096 K=1024), 2048 blocks
  gemm_kernel<0, 1024, 4096><<<2048, 256, 0, stream>>>(xb, Kb, P, nullptr, l);
  // out = (P @ Vt-rows) / l  (M=8192 N=1024 K=4096), 512 blocks
  gemm_kernel<1, 4096, 1024><<<512, 256, 0, stream>>>(P, Vt, nullptr, out, l);
}